// Round 1
// baseline (153.508 us; speedup 1.0000x reference)
//
#include <hip/hip_runtime.h>
#include <hip/hip_bf16.h>
#include <math.h>

// Problem: B=2, N=8192, M=8192, C=3, k=20; MLP 20->256->128->1 with BN+ReLU, sigmoid.
// Pipeline:
//   k_transpose_y : y [2][8192][3] -> ys [2][3][8192]  (SoA for float4 loads)
//   k_transpose_w2: W2 [128][256] -> W2T [256][128]    (for conflict-free LDS staging)
//   k_knn         : per-row top-20 smallest squared distance (one wave per row),
//                   per-lane sorted top-20 via v_med3_f32 branchless insert,
//                   cross-lane merge via LDS heads + wave-min + ballot.
//   k_mlp1        : h1[row][256] = relu(bn1(W1 . d))   (thread = out channel)
//   k_mlp2        : h2 GEMM [16384x256]@[256x128] + bn2 + relu + W3 dot (fused),
//                   W2 staged k-major in LDS, 4 rows x 4 outs per thread,
//                   partial sums per o-half -> ws
//   k_out         : sigmoid(p0+p1) -> d_out

#define M_CAND 8192
#define NROWS 16384
#define KSEL 20

__device__ __forceinline__ float med3f(float a, float b, float c) {
    return __builtin_amdgcn_fmed3f(a, b, c);
}

// ---------- kernel: transpose y to SoA ----------
__global__ __launch_bounds__(256) void k_transpose_y(const float* __restrict__ y,
                                                     float* __restrict__ ys) {
    int idx = blockIdx.x * 256 + threadIdx.x;     // 49152 total
    float v = y[idx];
    int b = idx / (M_CAND * 3);
    int rem = idx - b * (M_CAND * 3);
    int m = rem / 3;
    int c = rem - m * 3;
    ys[(b * 3 + c) * M_CAND + m] = v;
}

// ---------- kernel: transpose W2 ----------
__global__ __launch_bounds__(256) void k_transpose_w2(const float* __restrict__ w2,
                                                      float* __restrict__ w2t) {
    int idx = blockIdx.x * 256 + threadIdx.x;     // 32768 total
    int o = idx >> 8;
    int k = idx & 255;
    w2t[k * 128 + o] = w2[idx];
}

// ---------- kernel: kNN top-20 (one wave per row) ----------
__global__ __launch_bounds__(256) void k_knn(const float* __restrict__ x,
                                             const float* __restrict__ ys,
                                             float* __restrict__ dfeat) {
    __shared__ float sm[4][64 * 21];
    const int wid  = threadIdx.x >> 6;
    const int lane = threadIdx.x & 63;
    const int row  = blockIdx.x * 4 + wid;        // grid 4096 -> rows 0..16383
    const int b    = row >> 13;
    const float x0 = x[row * 3 + 0];
    const float x1 = x[row * 3 + 1];
    const float x2 = x[row * 3 + 2];
    const float* yb = ys + b * 3 * M_CAND;

    // ascending sorted top-20 of squared distances (smallest = nearest)
    float a[KSEL];
#pragma unroll
    for (int j = 0; j < KSEL; ++j) a[j] = 3.0e38f;

    for (int t = 0; t < M_CAND / 256; ++t) {
        const int mb = t * 256 + lane * 4;
        float4 v0 = *(const float4*)(yb + mb);
        float4 v1 = *(const float4*)(yb + M_CAND + mb);
        float4 v2 = *(const float4*)(yb + 2 * M_CAND + mb);
        const float* e0 = (const float*)&v0;
        const float* e1 = (const float*)&v1;
        const float* e2 = (const float*)&v2;
#pragma unroll
        for (int j = 0; j < 4; ++j) {
            float d0 = x0 - e0[j];
            float d1 = x1 - e1[j];
            float d2 = x2 - e2[j];
            float v = fmaf(d0, d0, fmaf(d1, d1, d2 * d2));
            // branchless sorted insert: 1 med3 per slot (all independent -> ILP)
#pragma unroll
            for (int jj = KSEL - 1; jj >= 1; --jj) a[jj] = med3f(v, a[jj - 1], a[jj]);
            a[0] = fminf(a[0], v);
        }
    }

    // cross-lane merge: 20 rounds of wave-min over per-lane sorted heads
    float* smw = sm[wid];
    float* myp = smw + lane * 21;
#pragma unroll
    for (int j = 0; j < KSEL; ++j) myp[j] = a[j];
    myp[KSEL] = 3.0e38f;                          // pad slot (max 20 pops per lane)
    __syncthreads();

    int ptr = 0;
    float sel = 0.0f;
    for (int r = 0; r < KSEL; ++r) {
        float head = myp[ptr];
        float mn = head;
#pragma unroll
        for (int off = 32; off >= 1; off >>= 1) mn = fminf(mn, __shfl_xor(mn, off, 64));
        unsigned long long ball = __ballot(head == mn);
        int winner = (int)__ffsll(ball) - 1;      // first lane holding min (tie-safe)
        ptr += (lane == winner) ? 1 : 0;
        if (lane == r) sel = mn;
    }
    // reference feat value = pd = -(squared distance), descending
    if (lane < KSEL) dfeat[row * KSEL + lane] = -sel;
}

// ---------- kernel: layer 1 (20 -> 256) ----------
__global__ __launch_bounds__(256) void k_mlp1(const float* __restrict__ dfeat,
                                              const float* __restrict__ W1,
                                              const float* __restrict__ g1,
                                              const float* __restrict__ be1,
                                              const float* __restrict__ mu1,
                                              const float* __restrict__ va1,
                                              float* __restrict__ h1g) {
    const int o = threadIdx.x;                    // 0..255 = out channel
    const int rowbase = blockIdx.x * 64;          // grid 256
    float w[KSEL];
#pragma unroll
    for (int j = 0; j < KSEL; j += 4) {
        float4 q = *(const float4*)(W1 + o * KSEL + j);
        w[j] = q.x; w[j + 1] = q.y; w[j + 2] = q.z; w[j + 3] = q.w;
    }
    const float s  = g1[o] * rsqrtf(va1[o] + 1e-5f);
    const float bc = be1[o] - mu1[o] * s;
    for (int r = 0; r < 64; ++r) {
        const float* dr = dfeat + (size_t)(rowbase + r) * KSEL;
        float dv[KSEL];
#pragma unroll
        for (int j = 0; j < KSEL; j += 4) {
            float4 q = *(const float4*)(dr + j);  // broadcast across block, L1-hot
            dv[j] = q.x; dv[j + 1] = q.y; dv[j + 2] = q.z; dv[j + 3] = q.w;
        }
        float acc0 = 0.f, acc1 = 0.f;
#pragma unroll
        for (int j = 0; j < KSEL; j += 2) {
            acc0 = fmaf(w[j], dv[j], acc0);
            acc1 = fmaf(w[j + 1], dv[j + 1], acc1);
        }
        float hv = fmaxf(0.f, fmaf(s, acc0 + acc1, bc));
        h1g[(size_t)(rowbase + r) * 256 + o] = hv;
    }
}

// ---------- kernel: layer 2 GEMM + bn2 + relu + W3 dot ----------
__global__ __launch_bounds__(256) void k_mlp2(const float* __restrict__ h1g,
                                              const float* __restrict__ W2T,
                                              const float* __restrict__ g2,
                                              const float* __restrict__ be2,
                                              const float* __restrict__ mu2,
                                              const float* __restrict__ va2,
                                              const float* __restrict__ W3,
                                              float* __restrict__ partial) {
    __shared__ float w2l[256 * 64];               // [k][oo] k-major, 64KB -> 2 blocks/CU
    const int t = threadIdx.x;
    const int ohalf = blockIdx.x & 1;             // grid 512 = 256 row-groups x 2 o-halves
    const int rowbase = (blockIdx.x >> 1) * 64;
    const int obase = ohalf * 64;

    // stage W2 slice k-major (from pre-transposed W2T: coalesced reads, aligned LDS writes)
    {
        const int oo4 = (t & 15) * 4;
        const int k0  = t >> 4;
        for (int i = 0; i < 16; ++i) {
            int k = k0 + 16 * i;
            float4 q = *(const float4*)(W2T + k * 128 + obase + oo4);
            *(float4*)(&w2l[k * 64 + oo4]) = q;
        }
    }
    __syncthreads();

    const int og = t & 15;                        // 4 outs: obase + og*4 + i
    const int rq = t >> 4;                        // 4 rows: rowbase + rq*4 + j
    float acc[4][4];
#pragma unroll
    for (int r = 0; r < 4; ++r)
#pragma unroll
        for (int i = 0; i < 4; ++i) acc[r][i] = 0.f;

    const float* hrow = h1g + (size_t)(rowbase + rq * 4) * 256;
    for (int kq = 0; kq < 64; ++kq) {
        const int k = kq * 4;
        float4 hq[4];
        hq[0] = *(const float4*)(hrow + 0 * 256 + k);
        hq[1] = *(const float4*)(hrow + 1 * 256 + k);
        hq[2] = *(const float4*)(hrow + 2 * 256 + k);
        hq[3] = *(const float4*)(hrow + 3 * 256 + k);
        float4 wq[4];
        wq[0] = *(const float4*)(&w2l[(k + 0) * 64 + og * 4]);
        wq[1] = *(const float4*)(&w2l[(k + 1) * 64 + og * 4]);
        wq[2] = *(const float4*)(&w2l[(k + 2) * 64 + og * 4]);
        wq[3] = *(const float4*)(&w2l[(k + 3) * 64 + og * 4]);
#pragma unroll
        for (int r = 0; r < 4; ++r) {
            const float* hh = (const float*)&hq[r];
#pragma unroll
            for (int kk = 0; kk < 4; ++kk) {
                const float* ww = (const float*)&wq[kk];
                const float hval = hh[kk];
#pragma unroll
                for (int i = 0; i < 4; ++i)
                    acc[r][i] = fmaf(hval, ww[i], acc[r][i]);
            }
        }
    }

    // epilogue: bn2 + relu + W3 weighting, reduce over og (16-lane groups in-wave)
    float s2v[4], b2v[4], w3v[4];
#pragma unroll
    for (int i = 0; i < 4; ++i) {
        const int o = obase + og * 4 + i;
        const float sv = g2[o] * rsqrtf(va2[o] + 1e-5f);
        s2v[i] = sv;
        b2v[i] = be2[o] - mu2[o] * sv;
        w3v[i] = W3[o];
    }
#pragma unroll
    for (int r = 0; r < 4; ++r) {
        float c = 0.f;
#pragma unroll
        for (int i = 0; i < 4; ++i) {
            float h2 = fmaxf(0.f, fmaf(s2v[i], acc[r][i], b2v[i]));
            c = fmaf(w3v[i], h2, c);
        }
#pragma unroll
        for (int off = 8; off >= 1; off >>= 1) c += __shfl_xor(c, off, 64);
        if (og == 0) partial[ohalf * NROWS + rowbase + rq * 4 + r] = c;
    }
}

// ---------- kernel: combine halves + sigmoid ----------
__global__ __launch_bounds__(256) void k_out(const float* __restrict__ partial,
                                             float* __restrict__ out) {
    int i = blockIdx.x * 256 + threadIdx.x;       // grid 64 -> 16384
    float z = partial[i] + partial[NROWS + i];
    out[i] = 1.0f / (1.0f + expf(-z));
}

extern "C" void kernel_launch(void* const* d_in, const int* in_sizes, int n_in,
                              void* d_out, int out_size, void* d_ws, size_t ws_size,
                              hipStream_t stream) {
    const float* x   = (const float*)d_in[0];
    const float* y   = (const float*)d_in[1];
    const float* W1  = (const float*)d_in[2];
    const float* g1  = (const float*)d_in[3];
    const float* be1 = (const float*)d_in[4];
    const float* mu1 = (const float*)d_in[5];
    const float* va1 = (const float*)d_in[6];
    const float* W2  = (const float*)d_in[7];
    const float* g2  = (const float*)d_in[8];
    const float* be2 = (const float*)d_in[9];
    const float* mu2 = (const float*)d_in[10];
    const float* va2 = (const float*)d_in[11];
    const float* W3  = (const float*)d_in[12];
    float* out = (float*)d_out;

    char* ws = (char*)d_ws;
    float* ys    = (float*)(ws);                                    // 196,608 B
    float* dfeat = (float*)(ws + 196608);                           // 1,310,720 B
    float* w2t   = (float*)(ws + 196608 + 1310720);                 // 131,072 B
    float* h1    = (float*)(ws + 196608 + 1310720 + 131072);        // 16,777,216 B
    float* part  = (float*)(ws + 196608 + 1310720 + 131072 + 16777216); // 131,072 B

    k_transpose_y <<<192, 256, 0, stream>>>(y, ys);
    k_transpose_w2<<<128, 256, 0, stream>>>(W2, w2t);
    k_knn         <<<4096, 256, 0, stream>>>(x, ys, dfeat);
    k_mlp1        <<<256, 256, 0, stream>>>(dfeat, W1, g1, be1, mu1, va1, h1);
    k_mlp2        <<<512, 256, 0, stream>>>(h1, w2t, g2, be2, mu2, va2, W3, part);
    k_out         <<<64, 256, 0, stream>>>(part, out);
}

// Round 2
// 117.184 us; speedup vs baseline: 1.3100x; 1.3100x over previous
//
#include <hip/hip_runtime.h>
#include <hip/hip_bf16.h>
#include <math.h>

// Problem: B=2, N=8192, M=8192, C=3, k=20; MLP 20->256->128->1 with BN+ReLU, sigmoid.
// Pipeline:
//   k_prep_y      : y [2][8192][3] -> ys4 [2][8192] float4 (y0,y1,y2,|y|^2)
//   k_transpose_w2: W2 [128][256] -> W2T [256][128]
//   k_knn         : per-row top-20 LARGEST pd = 2x.y - xx - yy (== -dist^2).
//                   One wave per row. Per-lane sorted top-8 (med3 chain, 8 ops)
//                   + cross-lane 20-round max-merge. Exactness guard: if any
//                   lane's 8-list was exhausted during the merge, redo this row
//                   with a full per-lane top-20 chain (provably exact, ~never).
//   k_mlp1        : h1[row][256] = relu(bn1(W1 . feat))
//   k_mlp2        : GEMM [16384x256]@[256x128] + bn2 + relu + W3 dot, fused
//   k_out         : sigmoid(p0+p1)

#define M_CAND 8192
#define NROWS 16384
#define KSEL 20
#define MPL 8            // per-lane list length (main path)

__device__ __forceinline__ float med3f(float a, float b, float c) {
    return __builtin_amdgcn_fmed3f(a, b, c);
}

// ---------- kernel: y -> float4 AoS with precomputed |y|^2 ----------
__global__ __launch_bounds__(256) void k_prep_y(const float* __restrict__ y,
                                                float4* __restrict__ ys4) {
    int idx = blockIdx.x * 256 + threadIdx.x;     // 16384 total
    float y0 = y[idx * 3 + 0];
    float y1 = y[idx * 3 + 1];
    float y2 = y[idx * 3 + 2];
    ys4[idx] = make_float4(y0, y1, y2, y0 * y0 + y1 * y1 + y2 * y2);
}

// ---------- kernel: transpose W2 ----------
__global__ __launch_bounds__(256) void k_transpose_w2(const float* __restrict__ w2,
                                                      float* __restrict__ w2t) {
    int idx = blockIdx.x * 256 + threadIdx.x;     // 32768 total
    int o = idx >> 8;
    int k = idx & 255;
    w2t[k * 128 + o] = w2[idx];
}

// ---------- kernel: kNN top-20 by pd (one wave per row) ----------
__global__ __launch_bounds__(256, 4) void k_knn(const float* __restrict__ x,
                                                const float4* __restrict__ ys4,
                                                float* __restrict__ dfeat) {
    __shared__ float sm[4][64 * 21];              // per-wave region, dual stride 9/21
    const int wid  = threadIdx.x >> 6;
    const int lane = threadIdx.x & 63;
    const int row  = blockIdx.x * 4 + wid;        // grid 4096 -> rows 0..16383
    const int b    = row >> 13;
    const float x0 = x[row * 3 + 0];
    const float x1 = x[row * 3 + 1];
    const float x2 = x[row * 3 + 2];
    const float tx0 = 2.0f * x0, tx1 = 2.0f * x1, tx2 = 2.0f * x2;
    const float xxn = -(x0 * x0 + x1 * x1 + x2 * x2);
    const float4* yb = ys4 + b * M_CAND;

    // descending per-lane top-8 of pd (largest pd = nearest)
    float bl[MPL];
#pragma unroll
    for (int j = 0; j < MPL; ++j) bl[j] = -3.0e38f;

    for (int t = 0; t < M_CAND / 256; ++t) {
        const float4* p = yb + t * 256 + lane;    // 4 coalesced dwordx4 / lane / iter
        float4 cc[4];
        cc[0] = p[0]; cc[1] = p[64]; cc[2] = p[128]; cc[3] = p[192];
#pragma unroll
        for (int j = 0; j < 4; ++j) {
            float v = fmaf(tx0, cc[j].x, fmaf(tx1, cc[j].y, fmaf(tx2, cc[j].z, xxn))) - cc[j].w;
            // branchless sorted insert into descending list: 7 med3 + 1 max
#pragma unroll
            for (int jj = MPL - 1; jj >= 1; --jj) bl[jj] = med3f(v, bl[jj - 1], bl[jj]);
            bl[0] = fmaxf(bl[0], v);
        }
    }

    // cross-lane merge: 20 rounds of wave-max over per-lane sorted heads
    float* myp = sm[wid] + lane * (MPL + 1);      // stride 9: conflict-free
#pragma unroll
    for (int j = 0; j < MPL; ++j) myp[j] = bl[j];
    myp[MPL] = -3.0e38f;                          // pad slot
    asm volatile("s_waitcnt lgkmcnt(0)" ::: "memory");

    int ptr = 0;
    float sel = 0.0f;
    for (int r = 0; r < KSEL; ++r) {
        float head = myp[ptr];
        float mx = head;
#pragma unroll
        for (int off = 32; off >= 1; off >>= 1) mx = fmaxf(mx, __shfl_xor(mx, off, 64));
        unsigned long long ball = __ballot(head == mx);
        int winner = (int)__ffsll(ball) - 1;      // first lane holding max (tie-safe)
        ptr += (lane == winner) ? 1 : 0;
        if (lane == r) sel = mx;
    }

    // exactness guard: if any lane drained all 8 slots, its 9th value might
    // have belonged in the top-20 -> redo this row with full 20-slot lists.
    bool need_exact = (__ballot(ptr >= MPL) != 0ULL);
    if (need_exact) {
        float a[KSEL];
#pragma unroll
        for (int j = 0; j < KSEL; ++j) a[j] = -3.0e38f;
        for (int t = 0; t < M_CAND / 256; ++t) {
            const float4* p = yb + t * 256 + lane;
            float4 cc[4];
            cc[0] = p[0]; cc[1] = p[64]; cc[2] = p[128]; cc[3] = p[192];
#pragma unroll
            for (int j = 0; j < 4; ++j) {
                float v = fmaf(tx0, cc[j].x, fmaf(tx1, cc[j].y, fmaf(tx2, cc[j].z, xxn))) - cc[j].w;
#pragma unroll
                for (int jj = KSEL - 1; jj >= 1; --jj) a[jj] = med3f(v, a[jj - 1], a[jj]);
                a[0] = fmaxf(a[0], v);
            }
        }
        float* mq = sm[wid] + lane * (KSEL + 1);  // stride 21
#pragma unroll
        for (int j = 0; j < KSEL; ++j) mq[j] = a[j];
        mq[KSEL] = -3.0e38f;
        asm volatile("s_waitcnt lgkmcnt(0)" ::: "memory");
        int ptr2 = 0;
        for (int r = 0; r < KSEL; ++r) {
            float head = mq[ptr2];
            float mx = head;
#pragma unroll
            for (int off = 32; off >= 1; off >>= 1) mx = fmaxf(mx, __shfl_xor(mx, off, 64));
            unsigned long long ball = __ballot(head == mx);
            int winner = (int)__ffsll(ball) - 1;
            ptr2 += (lane == winner) ? 1 : 0;
            if (lane == r) sel = mx;
        }
    }

    // sel on lane r = r-th largest pd (descending) == reference top_k order
    if (lane < KSEL) dfeat[row * KSEL + lane] = sel;
}

// ---------- kernel: layer 1 (20 -> 256) ----------
__global__ __launch_bounds__(256) void k_mlp1(const float* __restrict__ dfeat,
                                              const float* __restrict__ W1,
                                              const float* __restrict__ g1,
                                              const float* __restrict__ be1,
                                              const float* __restrict__ mu1,
                                              const float* __restrict__ va1,
                                              float* __restrict__ h1g) {
    const int o = threadIdx.x;                    // 0..255 = out channel
    const int rowbase = blockIdx.x * 64;          // grid 256
    float w[KSEL];
#pragma unroll
    for (int j = 0; j < KSEL; j += 4) {
        float4 q = *(const float4*)(W1 + o * KSEL + j);
        w[j] = q.x; w[j + 1] = q.y; w[j + 2] = q.z; w[j + 3] = q.w;
    }
    const float s  = g1[o] * rsqrtf(va1[o] + 1e-5f);
    const float bc = be1[o] - mu1[o] * s;
    for (int r = 0; r < 64; ++r) {
        const float* dr = dfeat + (size_t)(rowbase + r) * KSEL;
        float dv[KSEL];
#pragma unroll
        for (int j = 0; j < KSEL; j += 4) {
            float4 q = *(const float4*)(dr + j);  // broadcast across block, L1-hot
            dv[j] = q.x; dv[j + 1] = q.y; dv[j + 2] = q.z; dv[j + 3] = q.w;
        }
        float acc0 = 0.f, acc1 = 0.f;
#pragma unroll
        for (int j = 0; j < KSEL; j += 2) {
            acc0 = fmaf(w[j], dv[j], acc0);
            acc1 = fmaf(w[j + 1], dv[j + 1], acc1);
        }
        float hv = fmaxf(0.f, fmaf(s, acc0 + acc1, bc));
        h1g[(size_t)(rowbase + r) * 256 + o] = hv;
    }
}

// ---------- kernel: layer 2 GEMM + bn2 + relu + W3 dot ----------
__global__ __launch_bounds__(256) void k_mlp2(const float* __restrict__ h1g,
                                              const float* __restrict__ W2T,
                                              const float* __restrict__ g2,
                                              const float* __restrict__ be2,
                                              const float* __restrict__ mu2,
                                              const float* __restrict__ va2,
                                              const float* __restrict__ W3,
                                              float* __restrict__ partial) {
    __shared__ float w2l[256 * 64];               // [k][oo] k-major
    const int t = threadIdx.x;
    const int ohalf = blockIdx.x & 1;             // grid 512
    const int rowbase = (blockIdx.x >> 1) * 64;
    const int obase = ohalf * 64;

    {
        const int oo4 = (t & 15) * 4;
        const int k0  = t >> 4;
        for (int i = 0; i < 16; ++i) {
            int k = k0 + 16 * i;
            float4 q = *(const float4*)(W2T + k * 128 + obase + oo4);
            *(float4*)(&w2l[k * 64 + oo4]) = q;
        }
    }
    __syncthreads();

    const int og = t & 15;
    const int rq = t >> 4;
    float acc[4][4];
#pragma unroll
    for (int r = 0; r < 4; ++r)
#pragma unroll
        for (int i = 0; i < 4; ++i) acc[r][i] = 0.f;

    const float* hrow = h1g + (size_t)(rowbase + rq * 4) * 256;
    for (int kq = 0; kq < 64; ++kq) {
        const int k = kq * 4;
        float4 hq[4];
        hq[0] = *(const float4*)(hrow + 0 * 256 + k);
        hq[1] = *(const float4*)(hrow + 1 * 256 + k);
        hq[2] = *(const float4*)(hrow + 2 * 256 + k);
        hq[3] = *(const float4*)(hrow + 3 * 256 + k);
        float4 wq[4];
        wq[0] = *(const float4*)(&w2l[(k + 0) * 64 + og * 4]);
        wq[1] = *(const float4*)(&w2l[(k + 1) * 64 + og * 4]);
        wq[2] = *(const float4*)(&w2l[(k + 2) * 64 + og * 4]);
        wq[3] = *(const float4*)(&w2l[(k + 3) * 64 + og * 4]);
#pragma unroll
        for (int r = 0; r < 4; ++r) {
            const float* hh = (const float*)&hq[r];
#pragma unroll
            for (int kk = 0; kk < 4; ++kk) {
                const float* ww = (const float*)&wq[kk];
                const float hval = hh[kk];
#pragma unroll
                for (int i = 0; i < 4; ++i)
                    acc[r][i] = fmaf(hval, ww[i], acc[r][i]);
            }
        }
    }

    float s2v[4], b2v[4], w3v[4];
#pragma unroll
    for (int i = 0; i < 4; ++i) {
        const int o = obase + og * 4 + i;
        const float sv = g2[o] * rsqrtf(va2[o] + 1e-5f);
        s2v[i] = sv;
        b2v[i] = be2[o] - mu2[o] * sv;
        w3v[i] = W3[o];
    }
#pragma unroll
    for (int r = 0; r < 4; ++r) {
        float c = 0.f;
#pragma unroll
        for (int i = 0; i < 4; ++i) {
            float h2 = fmaxf(0.f, fmaf(s2v[i], acc[r][i], b2v[i]));
            c = fmaf(w3v[i], h2, c);
        }
#pragma unroll
        for (int off = 8; off >= 1; off >>= 1) c += __shfl_xor(c, off, 64);
        if (og == 0) partial[ohalf * NROWS + rowbase + rq * 4 + r] = c;
    }
}

// ---------- kernel: combine halves + sigmoid ----------
__global__ __launch_bounds__(256) void k_out(const float* __restrict__ partial,
                                             float* __restrict__ out) {
    int i = blockIdx.x * 256 + threadIdx.x;       // grid 64 -> 16384
    float z = partial[i] + partial[NROWS + i];
    out[i] = 1.0f / (1.0f + expf(-z));
}

extern "C" void kernel_launch(void* const* d_in, const int* in_sizes, int n_in,
                              void* d_out, int out_size, void* d_ws, size_t ws_size,
                              hipStream_t stream) {
    const float* x   = (const float*)d_in[0];
    const float* y   = (const float*)d_in[1];
    const float* W1  = (const float*)d_in[2];
    const float* g1  = (const float*)d_in[3];
    const float* be1 = (const float*)d_in[4];
    const float* mu1 = (const float*)d_in[5];
    const float* va1 = (const float*)d_in[6];
    const float* W2  = (const float*)d_in[7];
    const float* g2  = (const float*)d_in[8];
    const float* be2 = (const float*)d_in[9];
    const float* mu2 = (const float*)d_in[10];
    const float* va2 = (const float*)d_in[11];
    const float* W3  = (const float*)d_in[12];
    float* out = (float*)d_out;

    char* ws = (char*)d_ws;
    float4* ys4  = (float4*)(ws);                                   // 262,144 B
    float* dfeat = (float*)(ws + 262144);                           // 1,310,720 B
    float* w2t   = (float*)(ws + 262144 + 1310720);                 // 131,072 B
    float* h1    = (float*)(ws + 262144 + 1310720 + 131072);        // 16,777,216 B
    float* part  = (float*)(ws + 262144 + 1310720 + 131072 + 16777216); // 131,072 B

    k_prep_y      <<<64, 256, 0, stream>>>(y, ys4);
    k_transpose_w2<<<128, 256, 0, stream>>>(W2, w2t);
    k_knn         <<<4096, 256, 0, stream>>>(x, ys4, dfeat);
    k_mlp1        <<<256, 256, 0, stream>>>(dfeat, W1, g1, be1, mu1, va1, h1);
    k_mlp2        <<<512, 256, 0, stream>>>(h1, w2t, g2, be2, mu2, va2, W3, part);
    k_out         <<<64, 256, 0, stream>>>(part, out);
}